// Round 8
// baseline (359.509 us; speedup 1.0000x reference)
//
#include <hip/hip_runtime.h>
#include <math.h>

#define BB 4
#define LL 1024
#define HID 512
#define NH 8
#define HD 64
#define PROJ 2048
#define NLAYER 2
#define TOK (BB*LL)          // 4096
#define QKV3 (3*NH*HD)       // 1536
#define LN_EPS 1e-5f

typedef unsigned short u16;
typedef unsigned int u32;
typedef _Float16 f16;
typedef __attribute__((ext_vector_type(8))) _Float16 half8;
typedef __attribute__((ext_vector_type(4))) float f32x4;

#define MFMAH(a,b,c) __builtin_amdgcn_mfma_f32_16x16x32_f16(a, b, c, 0, 0, 0)

__device__ inline u16 f16_rne(float x) {
    union { f16 h; u16 u; } c; c.h = (f16)x; return c.u;
}

// async global -> LDS, 16B per lane (lds dest wave-uniform base + lane*16)
__device__ __forceinline__ void gl16(const u16* g, u16* l) {
    __builtin_amdgcn_global_load_lds(
        (const __attribute__((address_space(1))) unsigned int*)(g),
        (__attribute__((address_space(3))) unsigned int*)(l),
        16, 0, 0);
}

// bijective XCD-chunk swizzle (m204)
__device__ inline int xcd_swz(int orig, int nwg) {
    int q = nwg >> 3, r = nwg & 7;
    int xcd = orig & 7, idx = orig >> 3;
    return (xcd < r) ? (xcd * (q + 1) + idx)
                     : (r * (q + 1) + (xcd - r) * q + idx);
}

// ---------------- reductions ----------------
__device__ inline float wave_sum(float v) {
#pragma unroll
    for (int m = 32; m; m >>= 1) v += __shfl_xor(v, m, 64);
    return v;
}

// ---------------- LayerNorm: f32 in -> f16 out ----------------
__global__ __launch_bounds__(256) void ln_kernel(
    const float* __restrict__ x, const float* __restrict__ g,
    const float* __restrict__ b, u16* __restrict__ y)
{
    __shared__ float red[4];
    int row = blockIdx.x;
    const float* xr = x + (size_t)row * HID;
    int t = threadIdx.x;
    int lane = t & 63, wid = t >> 6;
    float v0 = xr[t], v1 = xr[t + 256];
    float s = wave_sum(v0 + v1);
    if (lane == 0) red[wid] = s;
    __syncthreads();
    float mean = (red[0] + red[1] + red[2] + red[3]) * (1.0f / HID);
    __syncthreads();
    float d0 = v0 - mean, d1 = v1 - mean;
    s = wave_sum(d0 * d0 + d1 * d1);
    if (lane == 0) red[wid] = s;
    __syncthreads();
    float var = (red[0] + red[1] + red[2] + red[3]) * (1.0f / HID);
    float rstd = rsqrtf(var + LN_EPS);
    size_t o = (size_t)row * HID;
    y[o + t]       = f16_rne(d0 * rstd * g[t] + b[t]);
    y[o + t + 256] = f16_rne(d1 * rstd * g[t + 256] + b[t + 256]);
}

// ---------------- weight prep: W f32 [K][N] -> f16 [N][K] ----------------
__global__ __launch_bounds__(256) void wprep_kernel(
    const float* __restrict__ W, u16* __restrict__ Th, int K, int N)
{
    __shared__ float tile[32][33];
    int tx = threadIdx.x & 31, ty = threadIdx.x >> 5;  // 32 x 8
    int k0 = blockIdx.y * 32, n0 = blockIdx.x * 32;
#pragma unroll
    for (int r = 0; r < 32; r += 8)
        tile[ty + r][tx] = W[(size_t)(k0 + ty + r) * N + n0 + tx];
    __syncthreads();
#pragma unroll
    for (int r = 0; r < 32; r += 8) {
        float v = tile[tx][ty + r];          // = W[k0+tx][n0+ty+r]
        Th[(size_t)(n0 + ty + r) * K + k0 + tx] = f16_rne(v);
    }
}

// ---------------- f16 MFMA GEMM: 128x64 tile, BK=64 ----------------------
// C(MxN) = A(MxK) @ W(KxN) + bias. A f16 [M][K], W f16 [N][K].
// 256 thr = 4 waves (2x2), wave tile 64x32. LDS 24 KB single-buffered.
// Rows are 128B (64 f16): XOR chunk swizzle pc = lc ^ (row&7), pre-applied
// to the global source on stage (rule 21: same involution both sides).
// MODE 0: Ch = f16(x). MODE 1: atomicAdd(Cf,x) [split-K grid.z].
// MODE 2: relu, Ch = f16.
template<int MODE, int SK>
__global__ __launch_bounds__(256) void gemm8(
    const u16* __restrict__ A, const u16* __restrict__ B,
    const float* __restrict__ bias, float* __restrict__ Cf,
    u16* __restrict__ Ch, int M, int N, int K)
{
    __shared__ u16 sm[(128 + 64) * 64];   // A [128][64], B [64][64] at 8192
    int tid = threadIdx.x;
    int w = tid >> 6, lane = tid & 63;
    int hi = lane >> 4, lo16 = lane & 15;
    int wr = w >> 1, wc = w & 1;

    int gx = gridDim.x, nwg = gx * gridDim.y;
    int swz = xcd_swz(blockIdx.y * gx + blockIdx.x, nwg);
    int row0 = (swz / gx) * 128, col0 = (swz % gx) * 64;

    int kchunk = K / SK;
    int kbeg = blockIdx.z * kchunk;
    int nt = kchunk / 64;

    int srow = lane >> 3;                 // 0..7 within an 8-row gl16 slab
    int gcol = ((lane & 7) ^ srow) * 8;   // XOR-preswizzled source chunk

    f32x4 acc[4][2] = {};

    for (int t = 0; t < nt; ++t) {
        int k0 = kbeg + t * 64;
        __syncthreads();   // all waves done reading previous tile
        // stage A: wave w rows w*32 .. +31 (4 slabs of 8 rows)
#pragma unroll
        for (int c = 0; c < 4; ++c) {
            int r0 = w * 32 + c * 8;
            gl16(A + (size_t)(row0 + r0 + srow) * K + k0 + gcol, &sm[r0 * 64]);
        }
        // stage B: wave w rows w*16 .. +15 (2 slabs)
#pragma unroll
        for (int c = 0; c < 2; ++c) {
            int r0 = w * 16 + c * 8;
            gl16(B + (size_t)(col0 + r0 + srow) * K + k0 + gcol,
                 &sm[8192 + r0 * 64]);
        }
        __syncthreads();   // vmcnt(0) drain: tile resident

        half8 af[4][2], bf[2][2];
#pragma unroll
        for (int m = 0; m < 4; ++m) {
            int row = wr * 64 + m * 16 + lo16;
#pragma unroll
            for (int ks = 0; ks < 2; ++ks)
                af[m][ks] = *(const half8*)
                    &sm[row * 64 + (((ks * 4 + hi) ^ (row & 7)) * 8)];
        }
#pragma unroll
        for (int n = 0; n < 2; ++n) {
            int row = wc * 32 + n * 16 + lo16;
#pragma unroll
            for (int ks = 0; ks < 2; ++ks)
                bf[n][ks] = *(const half8*)
                    &sm[8192 + row * 64 + (((ks * 4 + hi) ^ (row & 7)) * 8)];
        }
#pragma unroll
        for (int m = 0; m < 4; ++m)
#pragma unroll
            for (int n = 0; n < 2; ++n)
#pragma unroll
                for (int ks = 0; ks < 2; ++ks)
                    acc[m][n] = MFMAH(af[m][ks], bf[n][ks], acc[m][n]);
    }

#pragma unroll
    for (int n = 0; n < 2; ++n) {
        int c = col0 + wc * 32 + n * 16 + lo16;
        float bv = (SK == 1 || blockIdx.z == 0) ? bias[c] : 0.0f;
#pragma unroll
        for (int m = 0; m < 4; ++m) {
            int rbase = row0 + wr * 64 + m * 16 + hi * 4;
#pragma unroll
            for (int r = 0; r < 4; ++r) {
                float x = acc[m][n][r] + bv;
                size_t idx = (size_t)(rbase + r) * N + c;
                if (MODE == 0) {
                    Ch[idx] = f16_rne(x);
                } else if (MODE == 1) {
                    unsafeAtomicAdd(&Cf[idx], x);
                } else {
                    Ch[idx] = f16_rne(fmaxf(x, 0.0f));
                }
            }
        }
    }
}

// ---------------- flash attention, MFMA f16 ----------------------------
// qkv: f16 [TOK][1536] (q|k|v, head h at h*64). out: av f16 [TOK][512].
__global__ __launch_bounds__(256) void attn_mfma(
    const u16* __restrict__ qkv, u16* __restrict__ avh)
{
    __shared__ u16 Ks[64 * 64];   // [k_tok][d], XOR-swizzled rows
    __shared__ u16 Vt[64 * 64];   // [d][k_tok], XOR-swizzled rows
    __shared__ u16 Pl[4 * 1024];  // per-wave [16 q][64 k], XOR-swizzled

    int gid = xcd_swz(blockIdx.x, gridDim.x);
    int qt = gid & 15;
    int bh = gid >> 4;
    int bb = bh >> 3, h = bh & 7;
    int tid = threadIdx.x;
    int w = tid >> 6, lane = tid & 63, hi = lane >> 4, lo16 = lane & 15;

    int qtok = bb * LL + qt * 64 + w * 16 + lo16;
    const u16* qsrc = qkv + (size_t)qtok * QKV3 + h * HD;
    half8 qf0 = *(const half8*)(qsrc + hi * 8);
    half8 qf1 = *(const half8*)(qsrc + 32 + hi * 8);

    f32x4 o[4] = {};
    float m_[4] = {-1e30f, -1e30f, -1e30f, -1e30f};
    float l_[4] = {0.f, 0.f, 0.f, 0.f};

    int stok = tid >> 2;          // staging token 0..63
    int spart = tid & 3;

    for (int kt = 0; kt <= qt; ++kt) {
        __syncthreads();  // previous tile fully consumed
        // ---- stage K tile
        {
            const u16* src = qkv + (size_t)(bb * LL + kt * 64 + stok) * QKV3 + HID + h * HD;
            int p0 = spart * 2;
#pragma unroll
            for (int pp = p0; pp < p0 + 2; ++pp) {
                uint4 v = *(const uint4*)(src + pp * 8);
                u32 dst = (u32)(stok * 128 + pp * 16) ^ ((stok & 7) << 4);
                *(uint4*)((char*)Ks + dst) = v;
            }
        }
        // ---- stage V tile transposed
        {
            const u16* src = qkv + (size_t)(bb * LL + kt * 64 + stok) * QKV3 + 2 * HID + h * HD;
            union { uint4 v; u16 s[8]; } x0, x1;
            x0.v = *(const uint4*)(src + spart * 16);
            x1.v = *(const uint4*)(src + spart * 16 + 8);
#pragma unroll
            for (int j = 0; j < 8; ++j) {
                int d = spart * 16 + j;
                u32 dst = (u32)(d * 128 + stok * 2) ^ ((d & 7) << 4);
                *(u16*)((char*)Vt + dst) = x0.s[j];
            }
#pragma unroll
            for (int j = 0; j < 8; ++j) {
                int d = spart * 16 + 8 + j;
                u32 dst = (u32)(d * 128 + stok * 2) ^ ((d & 7) << 4);
                *(u16*)((char*)Vt + dst) = x1.s[j];
            }
        }
        __syncthreads();

        // ---- QK^T
        f32x4 s[4];
#pragma unroll
        for (int n = 0; n < 4; ++n) {
            int tl = n * 16 + lo16;
            u32 off0 = (u32)(tl * 128 + hi * 16) ^ ((tl & 7) << 4);
            u32 off1 = (u32)(tl * 128 + 64 + hi * 16) ^ ((tl & 7) << 4);
            half8 kf0 = *(const half8*)((char*)Ks + off0);
            half8 kf1 = *(const half8*)((char*)Ks + off1);
            f32x4 z = {};
            z = MFMAH(qf0, kf0, z);
            z = MFMAH(qf1, kf1, z);
#pragma unroll
            for (int r = 0; r < 4; ++r) z[r] *= 0.125f;   // 1/sqrt(64)
            s[n] = z;
        }
        if (kt == qt) {
#pragma unroll
            for (int n = 0; n < 4; ++n) {
                int kl = n * 16 + lo16;
#pragma unroll
                for (int r = 0; r < 4; ++r) {
                    int ql = w * 16 + hi * 4 + r;
                    if (kl > ql) s[n][r] = -1e30f;
                }
            }
        }
        // ---- online softmax
        float mt[4];
#pragma unroll
        for (int r = 0; r < 4; ++r)
            mt[r] = fmaxf(fmaxf(s[0][r], s[1][r]), fmaxf(s[2][r], s[3][r]));
#pragma unroll
        for (int st = 1; st < 16; st <<= 1)
#pragma unroll
            for (int r = 0; r < 4; ++r)
                mt[r] = fmaxf(mt[r], __shfl_xor(mt[r], st, 64));
        float ps[4];
#pragma unroll
        for (int r = 0; r < 4; ++r) {
            float mn = fmaxf(m_[r], mt[r]);
            float f = __expf(m_[r] - mn);
            l_[r] *= f;
#pragma unroll
            for (int n = 0; n < 4; ++n) o[n][r] *= f;
            m_[r] = mn;
            ps[r] = 0.f;
        }
#pragma unroll
        for (int n = 0; n < 4; ++n)
#pragma unroll
            for (int r = 0; r < 4; ++r) {
                float p = __expf(s[n][r] - m_[r]);
                s[n][r] = p;
                ps[r] += p;
            }
#pragma unroll
        for (int st = 1; st < 16; st <<= 1)
#pragma unroll
            for (int r = 0; r < 4; ++r)
                ps[r] += __shfl_xor(ps[r], st, 64);
#pragma unroll
        for (int r = 0; r < 4; ++r) l_[r] += ps[r];

        // ---- P -> LDS (f16), per-wave private region
#pragma unroll
        for (int n = 0; n < 4; ++n) {
            int kl = n * 16 + lo16;
#pragma unroll
            for (int r = 0; r < 4; ++r) {
                int ql = hi * 4 + r;
                u32 off = (u32)(w * 2048) + (((u32)(ql * 128 + kl * 2)) ^ ((ql & 7) << 4));
                *(u16*)((char*)Pl + off) = f16_rne(s[n][r]);
            }
        }
        // ---- PV
        half8 pa[2];
#pragma unroll
        for (int c = 0; c < 2; ++c) {
            u32 off = (u32)(w * 2048) + (((u32)(lo16 * 128 + c * 64 + hi * 16)) ^ ((lo16 & 7) << 4));
            pa[c] = *(const half8*)((char*)Pl + off);
        }
#pragma unroll
        for (int n = 0; n < 4; ++n) {
            int dl = n * 16 + lo16;
            u32 ov0 = (u32)(dl * 128 + hi * 16) ^ ((dl & 7) << 4);
            u32 ov1 = (u32)(dl * 128 + 64 + hi * 16) ^ ((dl & 7) << 4);
            half8 vb0 = *(const half8*)((char*)Vt + ov0);
            half8 vb1 = *(const half8*)((char*)Vt + ov1);
            o[n] = MFMAH(pa[0], vb0, o[n]);
            o[n] = MFMAH(pa[1], vb1, o[n]);
        }
    }

    // ---- epilogue
#pragma unroll
    for (int r = 0; r < 4; ++r) {
        float inv = 1.0f / l_[r];
        int tokg = bb * LL + qt * 64 + w * 16 + hi * 4 + r;
#pragma unroll
        for (int n = 0; n < 4; ++n) {
            int d = n * 16 + lo16;
            avh[(size_t)tokg * (NH * HD) + h * HD + d] = f16_rne(o[n][r] * inv);
        }
    }
}

// ---------------- boundary decision + blend -----------------------------
__global__ __launch_bounds__(64) void bd_kernel(
    const float* __restrict__ outb, const float* __restrict__ layer_x,
    const float* __restrict__ mm, const float* __restrict__ bd_w,
    const float* __restrict__ bd_b, float* __restrict__ d_out)
{
    int t = blockIdx.x;
    int lane = threadIdx.x;
    const float* orow = outb + (size_t)t * HID;
    float dot = 0.0f;
#pragma unroll
    for (int i = 0; i < 8; ++i) dot += orow[lane + 64 * i] * bd_w[lane + 64 * i];
    dot = wave_sum(dot);
    float mmv = mm[t];
    const float* xrow = layer_x + (size_t)t * HID;
    float* yrow = d_out + (size_t)t * HID;
#pragma unroll
    for (int i = 0; i < 8; ++i) {
        int c = lane + 64 * i;
        yrow[c] = orow[c] * mmv + (1.0f - mmv) * xrow[c];
    }
    if (lane == 0) {
        float z = dot + bd_b[0];
        d_out[(size_t)TOK * HID + t] = (z > 0.0f) ? 1.0f : 0.0f;
    }
}

extern "C" void kernel_launch(void* const* d_in, const int* in_sizes, int n_in,
                              void* d_out, int out_size, void* d_ws, size_t ws_size,
                              hipStream_t stream) {
    const float* layer_x = (const float*)d_in[0];
    const float* mm      = (const float*)d_in[2];
    const float* qkv_w   = (const float*)d_in[3];
    const float* qkv_b   = (const float*)d_in[4];
    const float* o_w     = (const float*)d_in[5];
    const float* o_b     = (const float*)d_in[6];
    const float* ln1_g   = (const float*)d_in[7];
    const float* ln1_b   = (const float*)d_in[8];
    const float* ff_w1   = (const float*)d_in[9];
    const float* ff_b1   = (const float*)d_in[10];
    const float* ff_w2   = (const float*)d_in[11];
    const float* ff_b2   = (const float*)d_in[12];
    const float* ln2_g   = (const float*)d_in[13];
    const float* ln2_b   = (const float*)d_in[14];
    const float* bd_w    = (const float*)d_in[15];
    const float* bd_b    = (const float*)d_in[16];

    char* base = (char*)d_ws;
    float* buf_out = (float*)base;                 //  8388608 B
    u16* hbuf = (u16*)(base + 8388608);            //  4194304
    u16* av   = (u16*)(base + 12582912);           //  4194304
    u16* qkvb = (u16*)(base + 16777216);           // 12582912
    u16* tbuf = (u16*)(base + 29360128);           // 16777216
    u16* wt   = (u16*)(base + 46137344);           // 12582912
    size_t need = 58720256;
    if (ws_size < need) return;

    const size_t WST = 3145728;  // per-layer stride in wt region (elems)
    const size_t OFF_QKV = 0, OFF_O = 786432, OFF_FF1 = 1048576, OFF_FF2 = 2097152;

    // weight prep (transpose + f16)
    for (int l = 0; l < NLAYER; ++l) {
        size_t wb = (size_t)l * WST;
        wprep_kernel<<<dim3(QKV3 / 32, HID / 32), 256, 0, stream>>>(
            qkv_w + (size_t)l * HID * QKV3, wt + wb + OFF_QKV, HID, QKV3);
        wprep_kernel<<<dim3(HID / 32, HID / 32), 256, 0, stream>>>(
            o_w + (size_t)l * HID * HID, wt + wb + OFF_O, HID, HID);
        wprep_kernel<<<dim3(PROJ / 32, HID / 32), 256, 0, stream>>>(
            ff_w1 + (size_t)l * HID * PROJ, wt + wb + OFF_FF1, HID, PROJ);
        wprep_kernel<<<dim3(HID / 32, PROJ / 32), 256, 0, stream>>>(
            ff_w2 + (size_t)l * PROJ * HID, wt + wb + OFF_FF2, PROJ, HID);
    }

    hipMemcpyAsync(buf_out, layer_x, (size_t)TOK * HID * sizeof(float),
                   hipMemcpyDeviceToDevice, stream);

    for (int l = 0; l < NLAYER; ++l) {
        size_t wb = (size_t)l * WST;
        // h = LN1(out) -> f16
        ln_kernel<<<TOK, 256, 0, stream>>>(buf_out, ln1_g + (size_t)l * HID,
                                           ln1_b + (size_t)l * HID, hbuf);
        // qkv = h @ qkv_w + qkv_b  -> f16
        gemm8<0, 1><<<dim3(QKV3 / 64, TOK / 128, 1), 256, 0, stream>>>(
            hbuf, wt + wb + OFF_QKV, qkv_b + (size_t)l * QKV3,
            nullptr, qkvb, TOK, QKV3, HID);
        // av = softmax(q k^T / 8) v  -> f16
        attn_mfma<<<BB * NH * (LL / 64), 256, 0, stream>>>(qkvb, av);
        // out += av @ o_w + o_b   (split-K 4, nt=2)
        gemm8<1, 4><<<dim3(HID / 64, TOK / 128, 4), 256, 0, stream>>>(
            av, wt + wb + OFF_O, o_b + (size_t)l * HID,
            buf_out, nullptr, TOK, HID, NH * HD);
        // h = LN2(out) -> f16
        ln_kernel<<<TOK, 256, 0, stream>>>(buf_out, ln2_g + (size_t)l * HID,
                                           ln2_b + (size_t)l * HID, hbuf);
        // t = relu(h @ w1 + b1) -> f16  (nt=8)
        gemm8<2, 1><<<dim3(PROJ / 64, TOK / 128, 1), 256, 0, stream>>>(
            hbuf, wt + wb + OFF_FF1, ff_b1 + (size_t)l * PROJ,
            nullptr, tbuf, TOK, PROJ, HID);
        // out += t @ w2 + b2   (split-K 8, nt=4)
        gemm8<1, 8><<<dim3(HID / 64, TOK / 128, 8), 256, 0, stream>>>(
            tbuf, wt + wb + OFF_FF2, ff_b2 + (size_t)l * HID,
            buf_out, nullptr, TOK, HID, PROJ);
    }

    bd_kernel<<<TOK, 64, 0, stream>>>(buf_out, layer_x, mm, bd_w, bd_b,
                                      (float*)d_out);
}

// Round 9
// 268.504 us; speedup vs baseline: 1.3389x; 1.3389x over previous
//
#include <hip/hip_runtime.h>
#include <math.h>

#define BB 4
#define LL 1024
#define HID 512
#define NH 8
#define HD 64
#define PROJ 2048
#define NLAYER 2
#define TOK (BB*LL)          // 4096
#define QKV3 (3*NH*HD)       // 1536
#define LN_EPS 1e-5f
#define PSTRIDE ((size_t)TOK * HID)   // partial slice stride (2M f32)

typedef unsigned short u16;
typedef unsigned int u32;
typedef _Float16 f16;
typedef __attribute__((ext_vector_type(8))) _Float16 half8;
typedef __attribute__((ext_vector_type(4))) float f32x4;

#define MFMAH(a,b,c) __builtin_amdgcn_mfma_f32_16x16x32_f16(a, b, c, 0, 0, 0)

__device__ inline u16 f16_rne(float x) {
    union { f16 h; u16 u; } c; c.h = (f16)x; return c.u;
}

// async global -> LDS, 16B per lane (lds dest wave-uniform base + lane*16)
__device__ __forceinline__ void gl16(const u16* g, u16* l) {
    __builtin_amdgcn_global_load_lds(
        (const __attribute__((address_space(1))) unsigned int*)(g),
        (__attribute__((address_space(3))) unsigned int*)(l),
        16, 0, 0);
}

// bijective XCD-chunk swizzle (m204)
__device__ inline int xcd_swz(int orig, int nwg) {
    int q = nwg >> 3, r = nwg & 7;
    int xcd = orig & 7, idx = orig >> 3;
    return (xcd < r) ? (xcd * (q + 1) + idx)
                     : (r * (q + 1) + (xcd - r) * q + idx);
}

// ---------------- reductions ----------------
__device__ inline float wave_sum(float v) {
#pragma unroll
    for (int m = 32; m; m >>= 1) v += __shfl_xor(v, m, 64);
    return v;
}

// ---------------- LayerNorm (+ optional partial fold): f32 -> f16 -------
// FOLD>0: x[row] += sum_z P[z][row] first (in-place residual update).
template<int FOLD>
__global__ __launch_bounds__(256) void ln_kernel(
    float* __restrict__ x, const float* __restrict__ P,
    const float* __restrict__ g, const float* __restrict__ b,
    u16* __restrict__ y)
{
    __shared__ float red[4];
    int row = blockIdx.x;
    float* xr = x + (size_t)row * HID;
    int t = threadIdx.x;
    int lane = t & 63, wid = t >> 6;
    float v0 = xr[t], v1 = xr[t + 256];
    if (FOLD > 0) {
        size_t off = (size_t)row * HID + t;
#pragma unroll
        for (int z = 0; z < FOLD; ++z) {
            v0 += P[z * PSTRIDE + off];
            v1 += P[z * PSTRIDE + off + 256];
        }
        xr[t] = v0; xr[t + 256] = v1;
    }
    float s = wave_sum(v0 + v1);
    if (lane == 0) red[wid] = s;
    __syncthreads();
    float mean = (red[0] + red[1] + red[2] + red[3]) * (1.0f / HID);
    __syncthreads();
    float d0 = v0 - mean, d1 = v1 - mean;
    s = wave_sum(d0 * d0 + d1 * d1);
    if (lane == 0) red[wid] = s;
    __syncthreads();
    float var = (red[0] + red[1] + red[2] + red[3]) * (1.0f / HID);
    float rstd = rsqrtf(var + LN_EPS);
    size_t o = (size_t)row * HID;
    y[o + t]       = f16_rne(d0 * rstd * g[t] + b[t]);
    y[o + t + 256] = f16_rne(d1 * rstd * g[t + 256] + b[t + 256]);
}

// ---------------- weight prep: W f32 [K][N] -> f16 [N][K] ----------------
__global__ __launch_bounds__(256) void wprep_kernel(
    const float* __restrict__ W, u16* __restrict__ Th, int K, int N)
{
    __shared__ float tile[32][33];
    int tx = threadIdx.x & 31, ty = threadIdx.x >> 5;  // 32 x 8
    int k0 = blockIdx.y * 32, n0 = blockIdx.x * 32;
#pragma unroll
    for (int r = 0; r < 32; r += 8)
        tile[ty + r][tx] = W[(size_t)(k0 + ty + r) * N + n0 + tx];
    __syncthreads();
#pragma unroll
    for (int r = 0; r < 32; r += 8) {
        float v = tile[tx][ty + r];          // = W[k0+tx][n0+ty+r]
        Th[(size_t)(n0 + ty + r) * K + k0 + tx] = f16_rne(v);
    }
}

// ---------------- f16 MFMA GEMM: 128x64 tile, BK=64 ----------------------
// C(MxN) = A(MxK) @ W(KxN) + bias. A f16 [M][K], W f16 [N][K].
// 256 thr = 4 waves (2x2), wave tile 64x32. LDS 24 KB single-buffered.
// XOR chunk swizzle pc = lc ^ (row&7), pre-applied to the global source.
// MODE 0: Ch = f16(x). MODE 1: STREAMING f32 partial store to
//   Cf[blockIdx.z*M*N + idx] (no atomics; folded by the next LN/bd).
// MODE 2: relu, Ch = f16.
template<int MODE, int SK>
__global__ __launch_bounds__(256) void gemm9(
    const u16* __restrict__ A, const u16* __restrict__ B,
    const float* __restrict__ bias, float* __restrict__ Cf,
    u16* __restrict__ Ch, int M, int N, int K)
{
    __shared__ u16 sm[(128 + 64) * 64];   // A [128][64], B [64][64] at 8192
    int tid = threadIdx.x;
    int w = tid >> 6, lane = tid & 63;
    int hi = lane >> 4, lo16 = lane & 15;
    int wr = w >> 1, wc = w & 1;

    int gx = gridDim.x, nwg = gx * gridDim.y;
    int swz = xcd_swz(blockIdx.y * gx + blockIdx.x, nwg);
    int row0 = (swz / gx) * 128, col0 = (swz % gx) * 64;

    int kchunk = K / SK;
    int kbeg = blockIdx.z * kchunk;
    int nt = kchunk / 64;

    int srow = lane >> 3;                 // 0..7 within an 8-row gl16 slab
    int gcol = ((lane & 7) ^ srow) * 8;   // XOR-preswizzled source chunk

    f32x4 acc[4][2] = {};

    for (int t = 0; t < nt; ++t) {
        int k0 = kbeg + t * 64;
        __syncthreads();   // all waves done reading previous tile
#pragma unroll
        for (int c = 0; c < 4; ++c) {
            int r0 = w * 32 + c * 8;
            gl16(A + (size_t)(row0 + r0 + srow) * K + k0 + gcol, &sm[r0 * 64]);
        }
#pragma unroll
        for (int c = 0; c < 2; ++c) {
            int r0 = w * 16 + c * 8;
            gl16(B + (size_t)(col0 + r0 + srow) * K + k0 + gcol,
                 &sm[8192 + r0 * 64]);
        }
        __syncthreads();   // vmcnt(0) drain: tile resident

        half8 af[4][2], bf[2][2];
#pragma unroll
        for (int m = 0; m < 4; ++m) {
            int row = wr * 64 + m * 16 + lo16;
#pragma unroll
            for (int ks = 0; ks < 2; ++ks)
                af[m][ks] = *(const half8*)
                    &sm[row * 64 + (((ks * 4 + hi) ^ (row & 7)) * 8)];
        }
#pragma unroll
        for (int n = 0; n < 2; ++n) {
            int row = wc * 32 + n * 16 + lo16;
#pragma unroll
            for (int ks = 0; ks < 2; ++ks)
                bf[n][ks] = *(const half8*)
                    &sm[8192 + row * 64 + (((ks * 4 + hi) ^ (row & 7)) * 8)];
        }
#pragma unroll
        for (int m = 0; m < 4; ++m)
#pragma unroll
            for (int n = 0; n < 2; ++n)
#pragma unroll
                for (int ks = 0; ks < 2; ++ks)
                    acc[m][n] = MFMAH(af[m][ks], bf[n][ks], acc[m][n]);
    }

    size_t zoff = (size_t)blockIdx.z * M * N;
#pragma unroll
    for (int n = 0; n < 2; ++n) {
        int c = col0 + wc * 32 + n * 16 + lo16;
        float bv = (SK == 1 || blockIdx.z == 0) ? bias[c] : 0.0f;
#pragma unroll
        for (int m = 0; m < 4; ++m) {
            int rbase = row0 + wr * 64 + m * 16 + hi * 4;
#pragma unroll
            for (int r = 0; r < 4; ++r) {
                float x = acc[m][n][r] + bv;
                size_t idx = (size_t)(rbase + r) * N + c;
                if (MODE == 0) {
                    Ch[idx] = f16_rne(x);
                } else if (MODE == 1) {
                    Cf[zoff + idx] = x;          // streaming partial
                } else {
                    Ch[idx] = f16_rne(fmaxf(x, 0.0f));
                }
            }
        }
    }
}

// ---------------- flash attention, MFMA f16 ----------------------------
__global__ __launch_bounds__(256) void attn_mfma(
    const u16* __restrict__ qkv, u16* __restrict__ avh)
{
    __shared__ u16 Ks[64 * 64];   // [k_tok][d], XOR-swizzled rows
    __shared__ u16 Vt[64 * 64];   // [d][k_tok], XOR-swizzled rows
    __shared__ u16 Pl[4 * 1024];  // per-wave [16 q][64 k], XOR-swizzled

    int gid = xcd_swz(blockIdx.x, gridDim.x);
    int qt = gid & 15;
    int bh = gid >> 4;
    int bb = bh >> 3, h = bh & 7;
    int tid = threadIdx.x;
    int w = tid >> 6, lane = tid & 63, hi = lane >> 4, lo16 = lane & 15;

    int qtok = bb * LL + qt * 64 + w * 16 + lo16;
    const u16* qsrc = qkv + (size_t)qtok * QKV3 + h * HD;
    half8 qf0 = *(const half8*)(qsrc + hi * 8);
    half8 qf1 = *(const half8*)(qsrc + 32 + hi * 8);

    f32x4 o[4] = {};
    float m_[4] = {-1e30f, -1e30f, -1e30f, -1e30f};
    float l_[4] = {0.f, 0.f, 0.f, 0.f};

    int stok = tid >> 2;          // staging token 0..63
    int spart = tid & 3;

    for (int kt = 0; kt <= qt; ++kt) {
        __syncthreads();  // previous tile fully consumed
        // ---- stage K tile
        {
            const u16* src = qkv + (size_t)(bb * LL + kt * 64 + stok) * QKV3 + HID + h * HD;
            int p0 = spart * 2;
#pragma unroll
            for (int pp = p0; pp < p0 + 2; ++pp) {
                uint4 v = *(const uint4*)(src + pp * 8);
                u32 dst = (u32)(stok * 128 + pp * 16) ^ ((stok & 7) << 4);
                *(uint4*)((char*)Ks + dst) = v;
            }
        }
        // ---- stage V tile transposed
        {
            const u16* src = qkv + (size_t)(bb * LL + kt * 64 + stok) * QKV3 + 2 * HID + h * HD;
            union { uint4 v; u16 s[8]; } x0, x1;
            x0.v = *(const uint4*)(src + spart * 16);
            x1.v = *(const uint4*)(src + spart * 16 + 8);
#pragma unroll
            for (int j = 0; j < 8; ++j) {
                int d = spart * 16 + j;
                u32 dst = (u32)(d * 128 + stok * 2) ^ ((d & 7) << 4);
                *(u16*)((char*)Vt + dst) = x0.s[j];
            }
#pragma unroll
            for (int j = 0; j < 8; ++j) {
                int d = spart * 16 + 8 + j;
                u32 dst = (u32)(d * 128 + stok * 2) ^ ((d & 7) << 4);
                *(u16*)((char*)Vt + dst) = x1.s[j];
            }
        }
        __syncthreads();

        // ---- QK^T
        f32x4 s[4];
#pragma unroll
        for (int n = 0; n < 4; ++n) {
            int tl = n * 16 + lo16;
            u32 off0 = (u32)(tl * 128 + hi * 16) ^ ((tl & 7) << 4);
            u32 off1 = (u32)(tl * 128 + 64 + hi * 16) ^ ((tl & 7) << 4);
            half8 kf0 = *(const half8*)((char*)Ks + off0);
            half8 kf1 = *(const half8*)((char*)Ks + off1);
            f32x4 z = {};
            z = MFMAH(qf0, kf0, z);
            z = MFMAH(qf1, kf1, z);
#pragma unroll
            for (int r = 0; r < 4; ++r) z[r] *= 0.125f;   // 1/sqrt(64)
            s[n] = z;
        }
        if (kt == qt) {
#pragma unroll
            for (int n = 0; n < 4; ++n) {
                int kl = n * 16 + lo16;
#pragma unroll
                for (int r = 0; r < 4; ++r) {
                    int ql = w * 16 + hi * 4 + r;
                    if (kl > ql) s[n][r] = -1e30f;
                }
            }
        }
        // ---- online softmax
        float mt[4];
#pragma unroll
        for (int r = 0; r < 4; ++r)
            mt[r] = fmaxf(fmaxf(s[0][r], s[1][r]), fmaxf(s[2][r], s[3][r]));
#pragma unroll
        for (int st = 1; st < 16; st <<= 1)
#pragma unroll
            for (int r = 0; r < 4; ++r)
                mt[r] = fmaxf(mt[r], __shfl_xor(mt[r], st, 64));
        float ps[4];
#pragma unroll
        for (int r = 0; r < 4; ++r) {
            float mn = fmaxf(m_[r], mt[r]);
            float f = __expf(m_[r] - mn);
            l_[r] *= f;
#pragma unroll
            for (int n = 0; n < 4; ++n) o[n][r] *= f;
            m_[r] = mn;
            ps[r] = 0.f;
        }
#pragma unroll
        for (int n = 0; n < 4; ++n)
#pragma unroll
            for (int r = 0; r < 4; ++r) {
                float p = __expf(s[n][r] - m_[r]);
                s[n][r] = p;
                ps[r] += p;
            }
#pragma unroll
        for (int st = 1; st < 16; st <<= 1)
#pragma unroll
            for (int r = 0; r < 4; ++r)
                ps[r] += __shfl_xor(ps[r], st, 64);
#pragma unroll
        for (int r = 0; r < 4; ++r) l_[r] += ps[r];

        // ---- P -> LDS (f16), per-wave private region
#pragma unroll
        for (int n = 0; n < 4; ++n) {
            int kl = n * 16 + lo16;
#pragma unroll
            for (int r = 0; r < 4; ++r) {
                int ql = hi * 4 + r;
                u32 off = (u32)(w * 2048) + (((u32)(ql * 128 + kl * 2)) ^ ((ql & 7) << 4));
                *(u16*)((char*)Pl + off) = f16_rne(s[n][r]);
            }
        }
        // ---- PV
        half8 pa[2];
#pragma unroll
        for (int c = 0; c < 2; ++c) {
            u32 off = (u32)(w * 2048) + (((u32)(lo16 * 128 + c * 64 + hi * 16)) ^ ((lo16 & 7) << 4));
            pa[c] = *(const half8*)((char*)Pl + off);
        }
#pragma unroll
        for (int n = 0; n < 4; ++n) {
            int dl = n * 16 + lo16;
            u32 ov0 = (u32)(dl * 128 + hi * 16) ^ ((dl & 7) << 4);
            u32 ov1 = (u32)(dl * 128 + 64 + hi * 16) ^ ((dl & 7) << 4);
            half8 vb0 = *(const half8*)((char*)Vt + ov0);
            half8 vb1 = *(const half8*)((char*)Vt + ov1);
            o[n] = MFMAH(pa[0], vb0, o[n]);
            o[n] = MFMAH(pa[1], vb1, o[n]);
        }
    }

    // ---- epilogue
#pragma unroll
    for (int r = 0; r < 4; ++r) {
        float inv = 1.0f / l_[r];
        int tokg = bb * LL + qt * 64 + w * 16 + hi * 4 + r;
#pragma unroll
        for (int n = 0; n < 4; ++n) {
            int d = n * 16 + lo16;
            avh[(size_t)tokg * (NH * HD) + h * HD + d] = f16_rne(o[n][r] * inv);
        }
    }
}

// ---------------- boundary decision + blend (+ partial fold) -------------
template<int FOLD>
__global__ __launch_bounds__(64) void bd_kernel(
    const float* __restrict__ outb, const float* __restrict__ P,
    const float* __restrict__ layer_x, const float* __restrict__ mm,
    const float* __restrict__ bd_w, const float* __restrict__ bd_b,
    float* __restrict__ d_out)
{
    int t = blockIdx.x;
    int lane = threadIdx.x;
    const float* orow = outb + (size_t)t * HID;
    float mmv = mm[t];
    const float* xrow = layer_x + (size_t)t * HID;
    float* yrow = d_out + (size_t)t * HID;
    float dot = 0.0f;
#pragma unroll
    for (int i = 0; i < 8; ++i) {
        int c = lane + 64 * i;
        float v = orow[c];
        if (FOLD > 0) {
            size_t off = (size_t)t * HID + c;
#pragma unroll
            for (int z = 0; z < FOLD; ++z) v += P[z * PSTRIDE + off];
        }
        dot += v * bd_w[c];
        yrow[c] = v * mmv + (1.0f - mmv) * xrow[c];
    }
    dot = wave_sum(dot);
    if (lane == 0) {
        float z = dot + bd_b[0];
        d_out[(size_t)TOK * HID + t] = (z > 0.0f) ? 1.0f : 0.0f;
    }
}

extern "C" void kernel_launch(void* const* d_in, const int* in_sizes, int n_in,
                              void* d_out, int out_size, void* d_ws, size_t ws_size,
                              hipStream_t stream) {
    const float* layer_x = (const float*)d_in[0];
    const float* mm      = (const float*)d_in[2];
    const float* qkv_w   = (const float*)d_in[3];
    const float* qkv_b   = (const float*)d_in[4];
    const float* o_w     = (const float*)d_in[5];
    const float* o_b     = (const float*)d_in[6];
    const float* ff_w1   = (const float*)d_in[9];
    const float* ff_b1   = (const float*)d_in[10];
    const float* ff_w2   = (const float*)d_in[11];
    const float* ff_b2   = (const float*)d_in[12];
    const float* ln1_g   = (const float*)d_in[7];
    const float* ln1_b   = (const float*)d_in[8];
    const float* ln2_g   = (const float*)d_in[13];
    const float* ln2_b   = (const float*)d_in[14];
    const float* bd_w    = (const float*)d_in[15];
    const float* bd_b    = (const float*)d_in[16];

    char* base = (char*)d_ws;
    float* buf_out = (float*)base;                 //  8388608 B
    u16* hbuf = (u16*)(base + 8388608);            //  4194304
    u16* av   = (u16*)(base + 12582912);           //  4194304
    u16* big  = (u16*)(base + 16777216);           // 16777216 (qkvb | tbuf)
    u16* wt   = (u16*)(base + 33554432);           // 12582912
    float* part = (float*)(base + 46137344);       // 33554432 (4 x 8MB)
    size_t need = 79691776;
    if (ws_size < need) return;
    u16* qkvb = big;
    u16* tbuf = big;

    const size_t WST = 3145728;  // per-layer stride in wt region (elems)
    const size_t OFF_QKV = 0, OFF_O = 786432, OFF_FF1 = 1048576, OFF_FF2 = 2097152;

    // weight prep (transpose + f16)
    for (int l = 0; l < NLAYER; ++l) {
        size_t wb = (size_t)l * WST;
        wprep_kernel<<<dim3(QKV3 / 32, HID / 32), 256, 0, stream>>>(
            qkv_w + (size_t)l * HID * QKV3, wt + wb + OFF_QKV, HID, QKV3);
        wprep_kernel<<<dim3(HID / 32, HID / 32), 256, 0, stream>>>(
            o_w + (size_t)l * HID * HID, wt + wb + OFF_O, HID, HID);
        wprep_kernel<<<dim3(PROJ / 32, HID / 32), 256, 0, stream>>>(
            ff_w1 + (size_t)l * HID * PROJ, wt + wb + OFF_FF1, HID, PROJ);
        wprep_kernel<<<dim3(HID / 32, PROJ / 32), 256, 0, stream>>>(
            ff_w2 + (size_t)l * PROJ * HID, wt + wb + OFF_FF2, PROJ, HID);
    }

    hipMemcpyAsync(buf_out, layer_x, (size_t)TOK * HID * sizeof(float),
                   hipMemcpyDeviceToDevice, stream);

    for (int l = 0; l < NLAYER; ++l) {
        size_t wb = (size_t)l * WST;
        // h = LN1(out [+ prev ff2 partials]) -> f16
        if (l == 0)
            ln_kernel<0><<<TOK, 256, 0, stream>>>(
                buf_out, nullptr, ln1_g, ln1_b, hbuf);
        else
            ln_kernel<4><<<TOK, 256, 0, stream>>>(
                buf_out, part, ln1_g + (size_t)l * HID,
                ln1_b + (size_t)l * HID, hbuf);
        // qkv = h @ qkv_w + qkv_b  -> f16
        gemm9<0, 1><<<dim3(QKV3 / 64, TOK / 128, 1), 256, 0, stream>>>(
            hbuf, wt + wb + OFF_QKV, qkv_b + (size_t)l * QKV3,
            nullptr, qkvb, TOK, QKV3, HID);
        // av = softmax(q k^T / 8) v  -> f16
        attn_mfma<<<BB * NH * (LL / 64), 256, 0, stream>>>(qkvb, av);
        // o partials: av @ o_w + o_b  (split-K 4, streaming)
        gemm9<1, 4><<<dim3(HID / 64, TOK / 128, 4), 256, 0, stream>>>(
            av, wt + wb + OFF_O, o_b + (size_t)l * HID,
            part, nullptr, TOK, HID, NH * HD);
        // h = LN2(out + o partials) -> f16
        ln_kernel<4><<<TOK, 256, 0, stream>>>(
            buf_out, part, ln2_g + (size_t)l * HID,
            ln2_b + (size_t)l * HID, hbuf);
        // t = relu(h @ w1 + b1) -> f16
        gemm9<2, 1><<<dim3(PROJ / 64, TOK / 128, 1), 256, 0, stream>>>(
            hbuf, wt + wb + OFF_FF1, ff_b1 + (size_t)l * PROJ,
            nullptr, tbuf, TOK, PROJ, HID);
        // ff2 partials: t @ w2 + b2  (split-K 4, streaming)
        gemm9<1, 4><<<dim3(HID / 64, TOK / 128, 4), 256, 0, stream>>>(
            tbuf, wt + wb + OFF_FF2, ff_b2 + (size_t)l * HID,
            part, nullptr, TOK, HID, PROJ);
    }

    // boundary decision + blend (folds final ff2 partials)
    bd_kernel<4><<<TOK, 64, 0, stream>>>(buf_out, part, layer_x, mm,
                                         bd_w, bd_b, (float*)d_out);
}